// Round 1
// baseline (904.293 us; speedup 1.0000x reference)
//
#include <hip/hip_runtime.h>
#include <hip/hip_bf16.h>
#include <math.h>

typedef unsigned short u16;
typedef unsigned int u32;
typedef __bf16 v8bf __attribute__((ext_vector_type(8)));
typedef float v4f __attribute__((ext_vector_type(4)));

constexpr int BATCH = 2;
constexpr int SEQ = 2048;
constexpr int HID = 1024;
constexpr int NHEAD = 16;
constexpr int HDIM = 64;
constexpr int MROWS = BATCH * SEQ;          // 4096
constexpr int BIAS_LD = 2 * 1024 + 1;       // 2049
constexpr size_t BIAS_HSTRIDE = (size_t)BIAS_LD * BIAS_LD;

__device__ __forceinline__ u16 f2bf(float f) {
    u32 u = __builtin_bit_cast(u32, f);
    u32 r = u + 0x7fffu + ((u >> 16) & 1u);   // RNE
    return (u16)(r >> 16);
}

// swizzled LDS chunk offsets (16B chunks). Row-major [R][C] bf16 tile,
// chunk index within row XORed with low row bits -> conflict-free b128 frag reads.
__device__ __forceinline__ int swoff8(int row, int chunk)  { return (row * 8  + (chunk ^ (row & 7)))  << 4; }
__device__ __forceinline__ int swoff16(int row, int chunk) { return (row * 16 + (chunk ^ (row & 15))) << 4; }

__device__ __forceinline__ float2 blockreduce2(float a, float b) {
    #pragma unroll
    for (int m = 1; m < 64; m <<= 1) {
        a += __shfl_xor(a, m, 64);
        b += __shfl_xor(b, m, 64);
    }
    __shared__ float la[4], lb[4];
    int w = threadIdx.x >> 6;
    if ((threadIdx.x & 63) == 0) { la[w] = a; lb[w] = b; }
    __syncthreads();
    a = la[0] + la[1] + la[2] + la[3];
    b = lb[0] + lb[1] + lb[2] + lb[3];
    __syncthreads();
    return make_float2(a, b);
}

// ---------------- weight transpose + fp32 -> bf16:  W[K,N] -> Wt[N,K] ----------------
__global__ __launch_bounds__(256) void k_wt(const float* __restrict__ W, u16* __restrict__ Wt, int K, int N) {
    __shared__ float t[32][33];
    int n0 = blockIdx.x * 32, k0 = blockIdx.y * 32;
    int tx = threadIdx.x & 31, ty = threadIdx.x >> 5;  // 32 x 8
    #pragma unroll
    for (int i = 0; i < 32; i += 8) t[ty + i][tx] = W[(size_t)(k0 + ty + i) * N + n0 + tx];
    __syncthreads();
    #pragma unroll
    for (int i = 0; i < 32; i += 8) Wt[(size_t)(n0 + ty + i) * K + k0 + tx] = f2bf(t[tx][ty + i]);
}

// ---------------- pe (Linear(1->H)+LN) + add + LN -> x (bf16) ----------------
__global__ __launch_bounds__(256) void k_prenorm(const float* __restrict__ hidden,
        const float* __restrict__ pe_w, const float* __restrict__ pe_b,
        const float* __restrict__ pe_g, const float* __restrict__ pe_beta,
        const float* __restrict__ ng, const float* __restrict__ nb, u16* __restrict__ xbf) {
    int row = blockIdx.x;                 // b*SEQ + s
    int s = row & (SEQ - 1);
    float pos = ((float)s - 1024.0f) * (1.0f / 1024.0f);
    int t = threadIdx.x;
    float v[4];
    float s1 = 0.f, s2 = 0.f;
    #pragma unroll
    for (int i = 0; i < 4; i++) {
        int hh = i * 256 + t;
        float x = pos * pe_w[hh] + pe_b[hh];
        v[i] = x; s1 += x; s2 += x * x;
    }
    float2 red = blockreduce2(s1, s2);
    float mean = red.x * (1.f / HID);
    float var  = red.y * (1.f / HID) - mean * mean;
    float rstd = rsqrtf(var + 1e-5f);
    s1 = 0.f; s2 = 0.f;
    #pragma unroll
    for (int i = 0; i < 4; i++) {
        int hh = i * 256 + t;
        float pe = (v[i] - mean) * rstd * pe_g[hh] + pe_beta[hh];
        float x = hidden[(size_t)row * HID + hh] + pe;
        v[i] = x; s1 += x; s2 += x * x;
    }
    red = blockreduce2(s1, s2);
    mean = red.x * (1.f / HID);
    var  = red.y * (1.f / HID) - mean * mean;
    rstd = rsqrtf(var + 1e-5f);
    #pragma unroll
    for (int i = 0; i < 4; i++) {
        int hh = i * 256 + t;
        xbf[(size_t)row * HID + hh] = f2bf((v[i] - mean) * rstd * ng[hh] + nb[hh]);
    }
}

// ---------------- LN + ReLU: fp32 [rows][N] -> bf16 ----------------
__global__ __launch_bounds__(256) void k_ln_relu(const float* __restrict__ Z,
        const float* __restrict__ g, const float* __restrict__ be, u16* __restrict__ Y, int N) {
    int row = blockIdx.x, t = threadIdx.x;
    float v[8];
    float s1 = 0.f, s2 = 0.f;
    int c = N >> 8;
    #pragma unroll
    for (int i = 0; i < 8; i++) {
        if (i < c) {
            int hh = i * 256 + t;
            float x = Z[(size_t)row * N + hh];
            v[i] = x; s1 += x; s2 += x * x;
        }
    }
    float2 red = blockreduce2(s1, s2);
    float inv = 1.0f / (float)N;
    float mean = red.x * inv;
    float var  = red.y * inv - mean * mean;
    float rstd = rsqrtf(var + 1e-5f);
    #pragma unroll
    for (int i = 0; i < 8; i++) {
        if (i < c) {
            int hh = i * 256 + t;
            float y = (v[i] - mean) * rstd * g[hh] + be[hh];
            Y[(size_t)row * N + hh] = f2bf(fmaxf(y, 0.f));
        }
    }
}

// ---------------- V transpose: [b*S][H] -> [b][h][d][S] (bf16) ----------------
__global__ __launch_bounds__(256) void k_vtrans(const u16* __restrict__ V, u16* __restrict__ Vt) {
    __shared__ u16 t[64][68];
    int s0 = blockIdx.x * 64, h = blockIdx.y, b = blockIdx.z;
    int x = threadIdx.x & 63, y = threadIdx.x >> 6;
    #pragma unroll
    for (int i = 0; i < 64; i += 4) {
        int r = i + y;
        t[r][x] = V[(size_t)(b * SEQ + s0 + r) * HID + h * HDIM + x];
    }
    __syncthreads();
    size_t ob = (size_t)(b * NHEAD + h) * HDIM;
    #pragma unroll
    for (int i = 0; i < 64; i += 4) {
        int d = i + y;
        Vt[(ob + d) * SEQ + s0 + x] = t[x][d];
    }
}

// ---------------- bf16 MFMA GEMM: C[M,N] = A[M,K] @ Bt[N,K]^T + bias, *scale ----------------
// 128x128 tile, BK=64, 4 waves (2x2), each wave 4x4 16x16x32 MFMA tiles.
template <int OUT_BF16>
__global__ __launch_bounds__(256) void k_gemm(const u16* __restrict__ A, const u16* __restrict__ Bt,
        const float* __restrict__ bias, void* __restrict__ C, int N, int K, float scale) {
    __shared__ __align__(16) u16 lA[128 * 64];
    __shared__ __align__(16) u16 lB[128 * 64];
    char* lAc = (char*)lA;
    char* lBc = (char*)lB;
    const int m0 = blockIdx.x * 128, n0 = blockIdx.y * 128;
    const int tid = threadIdx.x, wave = tid >> 6, lane = tid & 63;
    const int wr = wave >> 1, wc = wave & 1, q4 = lane >> 4, ml = lane & 15;

    v4f acc[4][4];
    v4f zz = {0.f, 0.f, 0.f, 0.f};
    #pragma unroll
    for (int i = 0; i < 4; i++)
        #pragma unroll
        for (int j = 0; j < 4; j++) acc[i][j] = zz;

    for (int k0 = 0; k0 < K; k0 += 64) {
        __syncthreads();
        #pragma unroll
        for (int it = 0; it < 4; it++) {
            int c = tid + it * 256;
            int r = c >> 3, qc = c & 7;
            *(uint4*)(lAc + swoff8(r, qc)) = *(const uint4*)(A + (size_t)(m0 + r) * K + k0 + (qc << 3));
            *(uint4*)(lBc + swoff8(r, qc)) = *(const uint4*)(Bt + (size_t)(n0 + r) * K + k0 + (qc << 3));
        }
        __syncthreads();
        #pragma unroll
        for (int kk = 0; kk < 2; kk++) {
            v8bf af[4], bfv[4];
            #pragma unroll
            for (int i = 0; i < 4; i++) af[i] = *(const v8bf*)(lAc + swoff8(wr * 64 + i * 16 + ml, kk * 4 + q4));
            #pragma unroll
            for (int j = 0; j < 4; j++) bfv[j] = *(const v8bf*)(lBc + swoff8(wc * 64 + j * 16 + ml, kk * 4 + q4));
            #pragma unroll
            for (int i = 0; i < 4; i++)
                #pragma unroll
                for (int j = 0; j < 4; j++)
                    acc[i][j] = __builtin_amdgcn_mfma_f32_16x16x32_bf16(af[i], bfv[j], acc[i][j], 0, 0, 0);
        }
    }
    #pragma unroll
    for (int i = 0; i < 4; i++) {
        int rb = m0 + wr * 64 + i * 16 + q4 * 4;
        #pragma unroll
        for (int j = 0; j < 4; j++) {
            int col = n0 + wc * 64 + j * 16 + ml;
            float bv = bias[col];
            #pragma unroll
            for (int r = 0; r < 4; r++) {
                float val = (acc[i][j][r] + bv) * scale;
                if (OUT_BF16) ((u16*)C)[(size_t)(rb + r) * N + col] = f2bf(val);
                else          ((float*)C)[(size_t)(rb + r) * N + col] = val;
            }
        }
    }
}

// ---------------- flash attention with additive bias ----------------
// grid (b=2, qtile=16, h=16), block 256 (4 waves). Q-tile 128 (32 rows/wave), K-tile 128.
__global__ __launch_bounds__(256) void k_attn(const u16* __restrict__ Qm, const u16* __restrict__ Km,
        const u16* __restrict__ Vtm, const float* __restrict__ bias, u16* __restrict__ ctx) {
    __shared__ __align__(16) u16 lK[128 * 64];       // [key][d], swizzled (8 chunks/row)
    __shared__ __align__(16) u16 lV[64 * 128];       // [d][key], swizzled (16 chunks/row)
    __shared__ __align__(16) u16 lP[4][32 * 128];    // per-wave P, swizzled (16 chunks/row)
    int b = blockIdx.x, qt = blockIdx.y, h = blockIdx.z;
    int tid = threadIdx.x, wave = tid >> 6, lane = tid & 63;
    int q4 = lane >> 4, ml = lane & 15;
    char* lKc = (char*)lK;
    char* lVc = (char*)lV;
    char* lPc = (char*)lP[wave];

    // Q fragments (A-layout), pre-scaled by 1/8 at Q-GEMM epilogue
    v8bf qf[2][2];
    #pragma unroll
    for (int i = 0; i < 2; i++)
        #pragma unroll
        for (int kk = 0; kk < 2; kk++) {
            size_t row = (size_t)(b * SEQ + qt * 128 + wave * 32 + i * 16 + ml);
            qf[i][kk] = *(const v8bf*)(Qm + row * HID + h * HDIM + kk * 32 + q4 * 8);
        }

    float mr[2][4], lr[2][4];
    v4f o[2][4];
    v4f zz = {0.f, 0.f, 0.f, 0.f};
    #pragma unroll
    for (int i = 0; i < 2; i++)
        #pragma unroll
        for (int r = 0; r < 4; r++) { mr[i][r] = -1e30f; lr[i][r] = 0.f; }
    #pragma unroll
    for (int i = 0; i < 2; i++)
        #pragma unroll
        for (int n = 0; n < 4; n++) o[i][n] = zz;

    const float* bh = bias + (size_t)h * BIAS_HSTRIDE;
    const u16* Kb = Km + (size_t)b * SEQ * HID + h * HDIM;
    const u16* Vb = Vtm + (size_t)(b * NHEAD + h) * HDIM * SEQ;

    for (int kt = 0; kt < SEQ / 128; ++kt) {
        int k0 = kt * 128;
        __syncthreads();
        #pragma unroll
        for (int it = 0; it < 4; it++) {
            int c = tid + it * 256;
            {
                int r = c >> 3, qc = c & 7;
                *(uint4*)(lKc + swoff8(r, qc)) = *(const uint4*)(Kb + (size_t)(k0 + r) * HID + (qc << 3));
            }
            {
                int r = c >> 4, qc = c & 15;
                *(uint4*)(lVc + swoff16(r, qc)) = *(const uint4*)(Vb + (size_t)r * SEQ + k0 + (qc << 3));
            }
        }
        __syncthreads();

        // S = Q K^T
        v4f sa[2][8];
        #pragma unroll
        for (int i = 0; i < 2; i++)
            #pragma unroll
            for (int j = 0; j < 8; j++) sa[i][j] = zz;
        #pragma unroll
        for (int j = 0; j < 8; j++) {
            v8bf kf0 = *(const v8bf*)(lKc + swoff8(j * 16 + ml, q4));
            v8bf kf1 = *(const v8bf*)(lKc + swoff8(j * 16 + ml, 4 + q4));
            #pragma unroll
            for (int i = 0; i < 2; i++) {
                sa[i][j] = __builtin_amdgcn_mfma_f32_16x16x32_bf16(qf[i][0], kf0, sa[i][j], 0, 0, 0);
                sa[i][j] = __builtin_amdgcn_mfma_f32_16x16x32_bf16(qf[i][1], kf1, sa[i][j], 0, 0, 0);
            }
        }
        // + window_pos_bias (read once from HBM, fp32)
        int qg0 = qt * 128 + wave * 32;
        #pragma unroll
        for (int i = 0; i < 2; i++)
            #pragma unroll
            for (int j = 0; j < 8; j++) {
                const float* bp = bh + (size_t)(qg0 + i * 16 + q4 * 4) * BIAS_LD + (k0 + j * 16 + ml);
                #pragma unroll
                for (int r = 0; r < 4; r++) sa[i][j][r] += bp[(size_t)r * BIAS_LD];
            }
        // online softmax
        #pragma unroll
        for (int i = 0; i < 2; i++)
            #pragma unroll
            for (int r = 0; r < 4; r++) {
                float mx = sa[i][0][r];
                #pragma unroll
                for (int j = 1; j < 8; j++) mx = fmaxf(mx, sa[i][j][r]);
                mx = fmaxf(mx, __shfl_xor(mx, 1, 64));
                mx = fmaxf(mx, __shfl_xor(mx, 2, 64));
                mx = fmaxf(mx, __shfl_xor(mx, 4, 64));
                mx = fmaxf(mx, __shfl_xor(mx, 8, 64));
                float mnew = fmaxf(mr[i][r], mx);
                float alpha = __expf(mr[i][r] - mnew);
                mr[i][r] = mnew;
                float rs = 0.f;
                #pragma unroll
                for (int j = 0; j < 8; j++) {
                    float p = __expf(sa[i][j][r] - mnew);
                    sa[i][j][r] = p;
                    rs += p;
                }
                rs += __shfl_xor(rs, 1, 64);
                rs += __shfl_xor(rs, 2, 64);
                rs += __shfl_xor(rs, 4, 64);
                rs += __shfl_xor(rs, 8, 64);
                lr[i][r] = lr[i][r] * alpha + rs;
                #pragma unroll
                for (int n = 0; n < 4; n++) o[i][n][r] *= alpha;
            }
        // P (C-layout) -> LDS bf16 (A-layout source), per-wave private region
        #pragma unroll
        for (int i = 0; i < 2; i++)
            #pragma unroll
            for (int j = 0; j < 8; j++) {
                int col = j * 16 + ml;
                #pragma unroll
                for (int r = 0; r < 4; r++) {
                    int row = i * 16 + q4 * 4 + r;
                    int off = row * 256 + ((((col >> 3)) ^ (row & 15)) << 4) + ((col & 7) << 1);
                    *(u16*)(lPc + off) = f2bf(sa[i][j][r]);
                }
            }
        // O += P V
        #pragma unroll
        for (int kk = 0; kk < 4; kk++) {
            v8bf pf[2];
            #pragma unroll
            for (int i = 0; i < 2; i++)
                pf[i] = *(const v8bf*)(lPc + swoff16(i * 16 + ml, kk * 4 + q4));
            #pragma unroll
            for (int n = 0; n < 4; n++) {
                v8bf vf = *(const v8bf*)(lVc + swoff16(n * 16 + ml, kk * 4 + q4));
                #pragma unroll
                for (int i = 0; i < 2; i++)
                    o[i][n] = __builtin_amdgcn_mfma_f32_16x16x32_bf16(pf[i], vf, o[i][n], 0, 0, 0);
            }
        }
    }
    // epilogue: normalize and store ctx
    #pragma unroll
    for (int i = 0; i < 2; i++)
        #pragma unroll
        for (int n = 0; n < 4; n++)
            #pragma unroll
            for (int r = 0; r < 4; r++) {
                float val = o[i][n][r] / lr[i][r];
                size_t row = (size_t)(b * SEQ + qt * 128 + wave * 32 + i * 16 + q4 * 4 + r);
                ctx[row * HID + h * HDIM + n * 16 + ml] = f2bf(val);
            }
}

extern "C" void kernel_launch(void* const* d_in, const int* in_sizes, int n_in,
                              void* d_out, int out_size, void* d_ws, size_t ws_size,
                              hipStream_t stream) {
    const float* hidden = (const float*)d_in[0];
    const float* wbias  = (const float*)d_in[1];
    const float* pe_w   = (const float*)d_in[2];
    const float* pe_b   = (const float*)d_in[3];
    const float* pe_g   = (const float*)d_in[4];
    const float* pe_be  = (const float*)d_in[5];
    const float* ng     = (const float*)d_in[6];
    const float* nb     = (const float*)d_in[7];
    const float* Wq = (const float*)d_in[8];  const float* bq = (const float*)d_in[9];
    const float* Wk = (const float*)d_in[10]; const float* bk = (const float*)d_in[11];
    const float* Wv = (const float*)d_in[12]; const float* bv = (const float*)d_in[13];
    const float* W1 = (const float*)d_in[14]; const float* b1 = (const float*)d_in[15];
    const float* g1 = (const float*)d_in[16]; const float* be1 = (const float*)d_in[17];
    const float* W2 = (const float*)d_in[18]; const float* b2 = (const float*)d_in[19];
    const float* g2 = (const float*)d_in[20]; const float* be2 = (const float*)d_in[21];
    const float* W3 = (const float*)d_in[22]; const float* b3 = (const float*)d_in[23];
    const float* g3 = (const float*)d_in[24]; const float* be3 = (const float*)d_in[25];
    const float* W4 = (const float*)d_in[26]; const float* b4 = (const float*)d_in[27];

    char* ws = (char*)d_ws;
    size_t off = 0;
    auto alloc = [&](size_t bytes) {
        char* p = ws + off;
        off += (bytes + 1023) & ~(size_t)1023;
        return p;
    };
    u16* wqt = (u16*)alloc((size_t)1024 * 1024 * 2);
    u16* wkt = (u16*)alloc((size_t)1024 * 1024 * 2);
    u16* wvt = (u16*)alloc((size_t)1024 * 1024 * 2);
    u16* w1t = (u16*)alloc((size_t)2048 * 1024 * 2);
    u16* w2t = (u16*)alloc((size_t)2048 * 2048 * 2);
    u16* w3t = (u16*)alloc((size_t)2048 * 2048 * 2);
    u16* w4t = (u16*)alloc((size_t)1024 * 2048 * 2);
    u16* xbf = (u16*)alloc((size_t)MROWS * HID * 2);
    char* qkv_region = ws + off;                      // z (fp32, 32MB) overlays q/k/v/vt after attention
    u16* qbf = (u16*)alloc((size_t)MROWS * HID * 2);
    u16* kbf = (u16*)alloc((size_t)MROWS * HID * 2);
    u16* vbf = (u16*)alloc((size_t)MROWS * HID * 2);
    u16* vtb = (u16*)alloc((size_t)MROWS * HID * 2);
    u16* ctx = (u16*)alloc((size_t)MROWS * HID * 2);
    u16* y1  = (u16*)alloc((size_t)MROWS * 2048 * 2);
    u16* y2  = (u16*)alloc((size_t)MROWS * 2048 * 2);
    float* z = (float*)qkv_region;                    // 4096*2048*4 = 32MB, dead QKV buffers

    dim3 blk(256);
    // weight transposes (fp32 -> bf16 [N,K])
    k_wt<<<dim3(32, 32), blk, 0, stream>>>(Wq, wqt, 1024, 1024);
    k_wt<<<dim3(32, 32), blk, 0, stream>>>(Wk, wkt, 1024, 1024);
    k_wt<<<dim3(32, 32), blk, 0, stream>>>(Wv, wvt, 1024, 1024);
    k_wt<<<dim3(64, 32), blk, 0, stream>>>(W1, w1t, 1024, 2048);
    k_wt<<<dim3(64, 64), blk, 0, stream>>>(W2, w2t, 2048, 2048);
    k_wt<<<dim3(64, 64), blk, 0, stream>>>(W3, w3t, 2048, 2048);
    k_wt<<<dim3(32, 64), blk, 0, stream>>>(W4, w4t, 2048, 1024);
    // x = LN(hidden + LN(pos*pe_w + pe_b))
    k_prenorm<<<MROWS, blk, 0, stream>>>(hidden, pe_w, pe_b, pe_g, pe_be, ng, nb, xbf);
    // QKV projections (Q pre-scaled by 1/sqrt(hd))
    k_gemm<1><<<dim3(32, 8), blk, 0, stream>>>(xbf, wqt, bq, qbf, 1024, 1024, 0.125f);
    k_gemm<1><<<dim3(32, 8), blk, 0, stream>>>(xbf, wkt, bk, kbf, 1024, 1024, 1.0f);
    k_gemm<1><<<dim3(32, 8), blk, 0, stream>>>(xbf, wvt, bv, vbf, 1024, 1024, 1.0f);
    // V -> [b][h][d][s]
    k_vtrans<<<dim3(32, 16, 2), blk, 0, stream>>>(vbf, vtb);
    // fused attention
    k_attn<<<dim3(2, 16, 16), blk, 0, stream>>>(qbf, kbf, vtb, wbias, ctx);
    // out_proj MLP
    k_gemm<0><<<dim3(32, 16), blk, 0, stream>>>(ctx, w1t, b1, z, 2048, 1024, 1.0f);
    k_ln_relu<<<MROWS, blk, 0, stream>>>(z, g1, be1, y1, 2048);
    k_gemm<0><<<dim3(32, 16), blk, 0, stream>>>(y1, w2t, b2, z, 2048, 2048, 1.0f);
    k_ln_relu<<<MROWS, blk, 0, stream>>>(z, g2, be2, y2, 2048);
    k_gemm<0><<<dim3(32, 16), blk, 0, stream>>>(y2, w3t, b3, z, 2048, 2048, 1.0f);
    k_ln_relu<<<MROWS, blk, 0, stream>>>(z, g3, be3, y1, 2048);
    k_gemm<0><<<dim3(32, 8), blk, 0, stream>>>(y1, w4t, b4, (float*)d_out, 1024, 2048, 1.0f);
}

// Round 2
// 897.937 us; speedup vs baseline: 1.0071x; 1.0071x over previous
//
#include <hip/hip_runtime.h>
#include <hip/hip_bf16.h>
#include <stdint.h>
#include <math.h>

typedef unsigned short u16;
typedef unsigned int u32;
typedef __bf16 v8bf __attribute__((ext_vector_type(8)));
typedef float v4f __attribute__((ext_vector_type(4)));

constexpr int BATCH = 2;
constexpr int SEQ = 2048;
constexpr int HID = 1024;
constexpr int NHEAD = 16;
constexpr int HDIM = 64;
constexpr int MROWS = BATCH * SEQ;          // 4096
constexpr int QKV_LD = 3 * HID;             // 3072
constexpr int BIAS_LD = 2 * 1024 + 1;       // 2049
constexpr size_t BIAS_HSTRIDE = (size_t)BIAS_LD * BIAS_LD;

__device__ __forceinline__ u16 f2bf(float f) {
    u32 u = __builtin_bit_cast(u32, f);
    u32 r = u + 0x7fffu + ((u >> 16) & 1u);   // RNE
    return (u16)(r >> 16);
}
__device__ __forceinline__ float bf2f(u16 h) {
    return __builtin_bit_cast(float, (u32)h << 16);
}

// async global->LDS, 16B per lane. LDS dst = wave-uniform base + lane*16.
__device__ __forceinline__ void gld16(const void* g, void* lds_base) {
    __builtin_amdgcn_global_load_lds(
        (const __attribute__((address_space(1))) u32*)(uintptr_t)g,
        (__attribute__((address_space(3))) u32*)(u32)(uintptr_t)lds_base,
        16, 0, 0);
}

// swizzled LDS chunk offsets (16B chunks): position c in row r holds chunk c^(r&mask)
__device__ __forceinline__ int swoff8(int row, int chunk)  { return (row * 8  + (chunk ^ (row & 7)))  << 4; }
__device__ __forceinline__ int swoff16(int row, int chunk) { return (row * 16 + (chunk ^ (row & 15))) << 4; }

__device__ __forceinline__ float2 blockreduce2(float a, float b) {
    #pragma unroll
    for (int m = 1; m < 64; m <<= 1) {
        a += __shfl_xor(a, m, 64);
        b += __shfl_xor(b, m, 64);
    }
    __shared__ float la[4], lb[4];
    int w = threadIdx.x >> 6;
    if ((threadIdx.x & 63) == 0) { la[w] = a; lb[w] = b; }
    __syncthreads();
    a = la[0] + la[1] + la[2] + la[3];
    b = lb[0] + lb[1] + lb[2] + lb[3];
    __syncthreads();
    return make_float2(a, b);
}

// ---------------- weight transpose + fp32 -> bf16 (scaled):  W[K,N] -> Wt[N,K] ----------------
__global__ __launch_bounds__(256) void k_wt(const float* __restrict__ W, u16* __restrict__ Wt,
                                            int K, int N, float scale) {
    __shared__ float t[32][33];
    int n0 = blockIdx.x * 32, k0 = blockIdx.y * 32;
    int tx = threadIdx.x & 31, ty = threadIdx.x >> 5;  // 32 x 8
    #pragma unroll
    for (int i = 0; i < 32; i += 8) t[ty + i][tx] = W[(size_t)(k0 + ty + i) * N + n0 + tx];
    __syncthreads();
    #pragma unroll
    for (int i = 0; i < 32; i += 8) Wt[(size_t)(n0 + ty + i) * K + k0 + tx] = f2bf(t[tx][ty + i] * scale);
}

// ---------------- concat bias for fused QKV (q scaled by 1/8) ----------------
__global__ __launch_bounds__(256) void k_bcat(const float* __restrict__ bq, const float* __restrict__ bk,
                                              const float* __restrict__ bv, float* __restrict__ o) {
    int n = blockIdx.x * 256 + threadIdx.x;
    float v = (n < 1024) ? bq[n] * 0.125f : (n < 2048 ? bk[n - 1024] : bv[n - 2048]);
    o[n] = v;
}

// ---------------- pe (Linear(1->H)+LN) + add + LN -> x (bf16) ----------------
__global__ __launch_bounds__(256) void k_prenorm(const float* __restrict__ hidden,
        const float* __restrict__ pe_w, const float* __restrict__ pe_b,
        const float* __restrict__ pe_g, const float* __restrict__ pe_beta,
        const float* __restrict__ ng, const float* __restrict__ nb, u16* __restrict__ xbf) {
    int row = blockIdx.x;                 // b*SEQ + s
    int s = row & (SEQ - 1);
    float pos = ((float)s - 1024.0f) * (1.0f / 1024.0f);
    int t = threadIdx.x, hh = t * 4;
    float4 pw = *(const float4*)(pe_w + hh);
    float4 pb = *(const float4*)(pe_b + hh);
    float v[4] = { pos * pw.x + pb.x, pos * pw.y + pb.y, pos * pw.z + pb.z, pos * pw.w + pb.w };
    float s1 = 0.f, s2 = 0.f;
    #pragma unroll
    for (int i = 0; i < 4; i++) { s1 += v[i]; s2 += v[i] * v[i]; }
    float2 red = blockreduce2(s1, s2);
    float mean = red.x * (1.f / HID);
    float var  = red.y * (1.f / HID) - mean * mean;
    float rstd = rsqrtf(var + 1e-5f);
    float4 pg = *(const float4*)(pe_g + hh);
    float4 pbe = *(const float4*)(pe_beta + hh);
    float4 hv = *(const float4*)(hidden + (size_t)row * HID + hh);
    v[0] = hv.x + (v[0] - mean) * rstd * pg.x + pbe.x;
    v[1] = hv.y + (v[1] - mean) * rstd * pg.y + pbe.y;
    v[2] = hv.z + (v[2] - mean) * rstd * pg.z + pbe.z;
    v[3] = hv.w + (v[3] - mean) * rstd * pg.w + pbe.w;
    s1 = 0.f; s2 = 0.f;
    #pragma unroll
    for (int i = 0; i < 4; i++) { s1 += v[i]; s2 += v[i] * v[i]; }
    red = blockreduce2(s1, s2);
    mean = red.x * (1.f / HID);
    var  = red.y * (1.f / HID) - mean * mean;
    rstd = rsqrtf(var + 1e-5f);
    float4 gg = *(const float4*)(ng + hh);
    float4 bb = *(const float4*)(nb + hh);
    ushort4 o;
    o.x = f2bf((v[0] - mean) * rstd * gg.x + bb.x);
    o.y = f2bf((v[1] - mean) * rstd * gg.y + bb.y);
    o.z = f2bf((v[2] - mean) * rstd * gg.z + bb.z);
    o.w = f2bf((v[3] - mean) * rstd * gg.w + bb.w);
    *(ushort4*)(xbf + (size_t)row * HID + hh) = o;
}

// ---------------- LN + ReLU: bf16 [rows][2048] -> bf16, 8 elems/thread ----------------
__global__ __launch_bounds__(256) void k_ln_relu(const u16* __restrict__ Z,
        const float* __restrict__ g, const float* __restrict__ be, u16* __restrict__ Y) {
    const int N = 2048;
    int row = blockIdx.x, t = threadIdx.x, base = t * 8;
    union { uint4 q; u16 h[8]; } u;
    u.q = *(const uint4*)(Z + (size_t)row * N + base);
    float v[8];
    float s1 = 0.f, s2 = 0.f;
    #pragma unroll
    for (int i = 0; i < 8; i++) { v[i] = bf2f(u.h[i]); s1 += v[i]; s2 += v[i] * v[i]; }
    float2 red = blockreduce2(s1, s2);
    float mean = red.x * (1.f / N);
    float var  = red.y * (1.f / N) - mean * mean;
    float rstd = rsqrtf(var + 1e-5f);
    float4 g0 = *(const float4*)(g + base), g1 = *(const float4*)(g + base + 4);
    float4 b0 = *(const float4*)(be + base), b1 = *(const float4*)(be + base + 4);
    float gg[8] = { g0.x, g0.y, g0.z, g0.w, g1.x, g1.y, g1.z, g1.w };
    float bb[8] = { b0.x, b0.y, b0.z, b0.w, b1.x, b1.y, b1.z, b1.w };
    union { uint4 q; u16 h[8]; } o;
    #pragma unroll
    for (int i = 0; i < 8; i++) o.h[i] = f2bf(fmaxf((v[i] - mean) * rstd * gg[i] + bb[i], 0.f));
    *(uint4*)(Y + (size_t)row * N + base) = o.q;
}

// ---------------- V transpose: qkv[b*S][3072] (V block) -> [b][h][d][S] (bf16) ----------------
__global__ __launch_bounds__(256) void k_vtrans(const u16* __restrict__ QKV, u16* __restrict__ Vt) {
    __shared__ u16 t[64][68];
    int s0 = blockIdx.x * 64, h = blockIdx.y, b = blockIdx.z;
    int x = threadIdx.x & 63, y = threadIdx.x >> 6;
    #pragma unroll
    for (int i = 0; i < 64; i += 4) {
        int r = i + y;
        t[r][x] = QKV[(size_t)(b * SEQ + s0 + r) * QKV_LD + 2048 + h * HDIM + x];
    }
    __syncthreads();
    size_t ob = (size_t)(b * NHEAD + h) * HDIM;
    #pragma unroll
    for (int i = 0; i < 64; i += 4) {
        int d = i + y;
        Vt[(ob + d) * SEQ + s0 + x] = t[x][d];
    }
}

// ---------------- bf16 MFMA GEMM: C[M,N] = A[M,K] @ Bt[N,K]^T + bias ----------------
// 128x128 tile, BK=64, async global_load_lds staging (swizzle-inverted lane addressing).
template <int OUT_BF16>
__global__ __launch_bounds__(256, 3) void k_gemm(const u16* __restrict__ A, const u16* __restrict__ Bt,
        const float* __restrict__ bias, void* __restrict__ C, int N, int K) {
    __shared__ __align__(16) u16 lA[128 * 64];
    __shared__ __align__(16) u16 lB[128 * 64];
    char* lAc = (char*)lA;
    char* lBc = (char*)lB;
    const int m0 = blockIdx.x * 128, n0 = blockIdx.y * 128;
    const int tid = threadIdx.x, wave = tid >> 6, lane = tid & 63;
    const int wr = wave >> 1, wc = wave & 1, q4 = lane >> 4, ml = lane & 15;
    // staging lane constants: row-in-group, chunk (XOR-inverted so LDS ends up swizzled)
    const int srow = wave * 8 + (lane >> 3);
    const int sqc  = (lane & 7) ^ (lane >> 3);

    v4f acc[4][4];
    v4f zz = {0.f, 0.f, 0.f, 0.f};
    #pragma unroll
    for (int i = 0; i < 4; i++)
        #pragma unroll
        for (int j = 0; j < 4; j++) acc[i][j] = zz;

    for (int k0 = 0; k0 < K; k0 += 64) {
        __syncthreads();
        #pragma unroll
        for (int it = 0; it < 4; it++) {
            int r = it * 32 + srow;
            gld16(A  + (size_t)(m0 + r) * K + k0 + sqc * 8, lAc + (it * 32 + wave * 8) * 128);
            gld16(Bt + (size_t)(n0 + r) * K + k0 + sqc * 8, lBc + (it * 32 + wave * 8) * 128);
        }
        __syncthreads();
        #pragma unroll
        for (int kk = 0; kk < 2; kk++) {
            v8bf af[4], bfv[4];
            #pragma unroll
            for (int i = 0; i < 4; i++) af[i] = *(const v8bf*)(lAc + swoff8(wr * 64 + i * 16 + ml, kk * 4 + q4));
            #pragma unroll
            for (int j = 0; j < 4; j++) bfv[j] = *(const v8bf*)(lBc + swoff8(wc * 64 + j * 16 + ml, kk * 4 + q4));
            #pragma unroll
            for (int i = 0; i < 4; i++)
                #pragma unroll
                for (int j = 0; j < 4; j++)
                    acc[i][j] = __builtin_amdgcn_mfma_f32_16x16x32_bf16(af[i], bfv[j], acc[i][j], 0, 0, 0);
        }
    }
    #pragma unroll
    for (int i = 0; i < 4; i++) {
        int rb = m0 + wr * 64 + i * 16 + q4 * 4;
        #pragma unroll
        for (int j = 0; j < 4; j++) {
            int col = n0 + wc * 64 + j * 16 + ml;
            float bv = bias[col];
            #pragma unroll
            for (int r = 0; r < 4; r++) {
                float val = acc[i][j][r] + bv;
                if (OUT_BF16) ((u16*)C)[(size_t)(rb + r) * N + col] = f2bf(val);
                else          ((float*)C)[(size_t)(rb + r) * N + col] = val;
            }
        }
    }
}

// ---------------- flash attention with additive bias ----------------
// grid (b=2, qt=32, h=16), block 256 (4 waves). Q-tile 64 (16 rows/wave), K-tile 128.
// LDS: lK 16KB (async-staged) + per-wave lP 4KB. V^T fragments read from global (L2-resident).
__global__ __launch_bounds__(256, 3) void k_attn(const u16* __restrict__ QKV,
        const u16* __restrict__ Vtm, const float* __restrict__ bias, u16* __restrict__ ctx) {
    __shared__ __align__(16) u16 lK[128 * 64];       // [key][d], swizzled
    __shared__ __align__(16) u16 lP[4][16 * 128];    // per-wave P, swizzled (16 chunks/row)
    int b = blockIdx.x, qt = blockIdx.y, h = blockIdx.z;
    int tid = threadIdx.x, wave = tid >> 6, lane = tid & 63;
    int q4 = lane >> 4, ml = lane & 15;
    char* lKc = (char*)lK;
    char* lPc = (char*)lP[wave];
    const int qbase = qt * 64 + wave * 16;
    const int srow = wave * 8 + (lane >> 3);
    const int sqc  = (lane & 7) ^ (lane >> 3);

    const u16* Qb = QKV + (size_t)(b * SEQ) * QKV_LD + h * HDIM;
    const u16* Kb = QKV + (size_t)(b * SEQ) * QKV_LD + 1024 + h * HDIM;
    const u16* Vb = Vtm + (size_t)(b * NHEAD + h) * HDIM * SEQ;
    const float* bh = bias + (size_t)h * BIAS_HSTRIDE;

    // Q fragments (A-layout); 1/sqrt(hd) folded into Wq/bq upstream
    v8bf qf[2];
    #pragma unroll
    for (int kk = 0; kk < 2; kk++)
        qf[kk] = *(const v8bf*)(Qb + (size_t)(qbase + ml) * QKV_LD + kk * 32 + q4 * 8);

    float mr[4], lr[4];
    v4f o[4];
    v4f zz = {0.f, 0.f, 0.f, 0.f};
    #pragma unroll
    for (int r = 0; r < 4; r++) { mr[r] = -1e30f; lr[r] = 0.f; }
    #pragma unroll
    for (int n = 0; n < 4; n++) o[n] = zz;

    for (int kt = 0; kt < SEQ / 128; ++kt) {
        int k0 = kt * 128;
        __syncthreads();
        // async K staging
        #pragma unroll
        for (int it = 0; it < 4; it++) {
            int r = it * 32 + srow;
            gld16(Kb + (size_t)(k0 + r) * QKV_LD + sqc * 8, lKc + (it * 32 + wave * 8) * 128);
        }
        // bias prefetch into VGPRs (latency merges with staging drain at the barrier)
        float bv[4][8];
        const float* bp0 = bh + (size_t)(qbase + q4 * 4) * BIAS_LD + k0 + ml;
        #pragma unroll
        for (int r = 0; r < 4; r++)
            #pragma unroll
            for (int j = 0; j < 8; j++) bv[r][j] = bp0[(size_t)r * BIAS_LD + j * 16];
        __syncthreads();

        // S = Q K^T
        v4f sa[8];
        #pragma unroll
        for (int j = 0; j < 8; j++) sa[j] = zz;
        #pragma unroll
        for (int j = 0; j < 8; j++) {
            v8bf kf0 = *(const v8bf*)(lKc + swoff8(j * 16 + ml, q4));
            v8bf kf1 = *(const v8bf*)(lKc + swoff8(j * 16 + ml, 4 + q4));
            sa[j] = __builtin_amdgcn_mfma_f32_16x16x32_bf16(qf[0], kf0, sa[j], 0, 0, 0);
            sa[j] = __builtin_amdgcn_mfma_f32_16x16x32_bf16(qf[1], kf1, sa[j], 0, 0, 0);
        }
        // + bias, online softmax (reduce over k: 8 regs x 16 ml-lanes)
        #pragma unroll
        for (int r = 0; r < 4; r++) {
            float mx = -1e30f;
            #pragma unroll
            for (int j = 0; j < 8; j++) { sa[j][r] += bv[r][j]; mx = fmaxf(mx, sa[j][r]); }
            mx = fmaxf(mx, __shfl_xor(mx, 1, 64));
            mx = fmaxf(mx, __shfl_xor(mx, 2, 64));
            mx = fmaxf(mx, __shfl_xor(mx, 4, 64));
            mx = fmaxf(mx, __shfl_xor(mx, 8, 64));
            float mnew = fmaxf(mr[r], mx);
            float alpha = __expf(mr[r] - mnew);
            mr[r] = mnew;
            float rs = 0.f;
            #pragma unroll
            for (int j = 0; j < 8; j++) {
                float p = __expf(sa[j][r] - mnew);
                sa[j][r] = p;
                rs += p;
            }
            rs += __shfl_xor(rs, 1, 64);
            rs += __shfl_xor(rs, 2, 64);
            rs += __shfl_xor(rs, 4, 64);
            rs += __shfl_xor(rs, 8, 64);
            lr[r] = lr[r] * alpha + rs;
            #pragma unroll
            for (int n = 0; n < 4; n++) o[n][r] *= alpha;
        }
        // P (C-layout) -> per-wave LDS (A-layout source), no barrier needed
        #pragma unroll
        for (int j = 0; j < 8; j++) {
            int col = j * 16 + ml;
            #pragma unroll
            for (int r = 0; r < 4; r++) {
                int row = q4 * 4 + r;
                int off = row * 256 + (((col >> 3) ^ row) << 4) + ((col & 7) << 1);
                *(u16*)(lPc + off) = f2bf(sa[j][r]);
            }
        }
        // O += P V  (V^T fragments from global, prefetched one kk ahead)
        v8bf vfc[4], vfn[4];
        #pragma unroll
        for (int n = 0; n < 4; n++)
            vfc[n] = *(const v8bf*)(Vb + (size_t)(n * 16 + ml) * SEQ + k0 + q4 * 8);
        #pragma unroll
        for (int kk = 0; kk < 4; kk++) {
            if (kk < 3) {
                #pragma unroll
                for (int n = 0; n < 4; n++)
                    vfn[n] = *(const v8bf*)(Vb + (size_t)(n * 16 + ml) * SEQ + k0 + (kk + 1) * 32 + q4 * 8);
            }
            v8bf pf = *(const v8bf*)(lPc + swoff16(ml, kk * 4 + q4));
            #pragma unroll
            for (int n = 0; n < 4; n++)
                o[n] = __builtin_amdgcn_mfma_f32_16x16x32_bf16(pf, vfc[n], o[n], 0, 0, 0);
            #pragma unroll
            for (int n = 0; n < 4; n++) vfc[n] = vfn[n];
        }
    }
    // epilogue
    #pragma unroll
    for (int n = 0; n < 4; n++)
        #pragma unroll
        for (int r = 0; r < 4; r++) {
            size_t row = (size_t)(b * SEQ + qbase + q4 * 4 + r);
            ctx[row * HID + h * HDIM + n * 16 + ml] = f2bf(o[n][r] / lr[r]);
        }
}

extern "C" void kernel_launch(void* const* d_in, const int* in_sizes, int n_in,
                              void* d_out, int out_size, void* d_ws, size_t ws_size,
                              hipStream_t stream) {
    const float* hidden = (const float*)d_in[0];
    const float* wbias  = (const float*)d_in[1];
    const float* pe_w   = (const float*)d_in[2];
    const float* pe_b   = (const float*)d_in[3];
    const float* pe_g   = (const float*)d_in[4];
    const float* pe_be  = (const float*)d_in[5];
    const float* ng     = (const float*)d_in[6];
    const float* nb     = (const float*)d_in[7];
    const float* Wq = (const float*)d_in[8];  const float* bq = (const float*)d_in[9];
    const float* Wk = (const float*)d_in[10]; const float* bk = (const float*)d_in[11];
    const float* Wv = (const float*)d_in[12]; const float* bv = (const float*)d_in[13];
    const float* W1 = (const float*)d_in[14]; const float* b1 = (const float*)d_in[15];
    const float* g1 = (const float*)d_in[16]; const float* be1 = (const float*)d_in[17];
    const float* W2 = (const float*)d_in[18]; const float* b2 = (const float*)d_in[19];
    const float* g2 = (const float*)d_in[20]; const float* be2 = (const float*)d_in[21];
    const float* W3 = (const float*)d_in[22]; const float* b3 = (const float*)d_in[23];
    const float* g3 = (const float*)d_in[24]; const float* be3 = (const float*)d_in[25];
    const float* W4 = (const float*)d_in[26]; const float* b4 = (const float*)d_in[27];

    char* ws = (char*)d_ws;
    size_t off = 0;
    auto alloc = [&](size_t bytes) {
        char* p = ws + off;
        off += (bytes + 1023) & ~(size_t)1023;
        return p;
    };
    u16* wqkvt = (u16*)alloc((size_t)3072 * 1024 * 2);
    u16* w1t = (u16*)alloc((size_t)2048 * 1024 * 2);
    u16* w2t = (u16*)alloc((size_t)2048 * 2048 * 2);
    u16* w3t = (u16*)alloc((size_t)2048 * 2048 * 2);
    u16* w4t = (u16*)alloc((size_t)1024 * 2048 * 2);
    float* bqkv = (float*)alloc((size_t)3072 * 4);
    u16* xbf = (u16*)alloc((size_t)MROWS * HID * 2);
    u16* qkv = (u16*)alloc((size_t)MROWS * QKV_LD * 2);
    u16* vtb = (u16*)alloc((size_t)MROWS * HID * 2);
    u16* ctx = (u16*)alloc((size_t)MROWS * HID * 2);
    u16* zb  = (u16*)alloc((size_t)MROWS * 2048 * 2);
    u16* ya  = (u16*)alloc((size_t)MROWS * 2048 * 2);
    u16* yb  = (u16*)alloc((size_t)MROWS * 2048 * 2);

    dim3 blk(256);
    // weight transposes (fp32 -> bf16 [N,K]); 1/8 attention scale folded into Wq
    k_wt<<<dim3(32, 32), blk, 0, stream>>>(Wq, wqkvt, 1024, 1024, 0.125f);
    k_wt<<<dim3(32, 32), blk, 0, stream>>>(Wk, wqkvt + (size_t)1024 * 1024, 1024, 1024, 1.0f);
    k_wt<<<dim3(32, 32), blk, 0, stream>>>(Wv, wqkvt + (size_t)2048 * 1024, 1024, 1024, 1.0f);
    k_wt<<<dim3(64, 32), blk, 0, stream>>>(W1, w1t, 1024, 2048, 1.0f);
    k_wt<<<dim3(64, 64), blk, 0, stream>>>(W2, w2t, 2048, 2048, 1.0f);
    k_wt<<<dim3(64, 64), blk, 0, stream>>>(W3, w3t, 2048, 2048, 1.0f);
    k_wt<<<dim3(32, 64), blk, 0, stream>>>(W4, w4t, 2048, 1024, 1.0f);
    k_bcat<<<dim3(12), blk, 0, stream>>>(bq, bk, bv, bqkv);
    // x = LN(hidden + LN(pos*pe_w + pe_b))
    k_prenorm<<<MROWS, blk, 0, stream>>>(hidden, pe_w, pe_b, pe_g, pe_be, ng, nb, xbf);
    // fused QKV projection -> qkv [4096][3072]
    k_gemm<1><<<dim3(32, 24), blk, 0, stream>>>(xbf, wqkvt, bqkv, qkv, QKV_LD, 1024);
    // V -> [b][h][d][s]
    k_vtrans<<<dim3(32, 16, 2), blk, 0, stream>>>(qkv, vtb);
    // fused attention
    k_attn<<<dim3(2, 32, 16), blk, 0, stream>>>(qkv, vtb, wbias, ctx);
    // out_proj MLP (bf16 intermediates)
    k_gemm<1><<<dim3(32, 16), blk, 0, stream>>>(ctx, w1t, b1, zb, 2048, 1024);
    k_ln_relu<<<MROWS, blk, 0, stream>>>(zb, g1, be1, ya);
    k_gemm<1><<<dim3(32, 16), blk, 0, stream>>>(ya, w2t, b2, zb, 2048, 2048);
    k_ln_relu<<<MROWS, blk, 0, stream>>>(zb, g2, be2, yb);
    k_gemm<1><<<dim3(32, 16), blk, 0, stream>>>(yb, w3t, b3, zb, 2048, 2048);
    k_ln_relu<<<MROWS, blk, 0, stream>>>(zb, g3, be3, ya);
    k_gemm<0><<<dim3(32, 8), blk, 0, stream>>>(ya, w4t, b4, (float*)d_out, 1024, 2048);
}